// Round 12
// baseline (97.962 us; speedup 1.0000x reference)
//
#include <hip/hip_runtime.h>
#include <hip/hip_fp16.h>

#define DIM 256
#define NC 16
#define NG 1000
#define CHUNK 6250      // 512 * 6250 = 3.2M exactly -> 1 chunk per block
#define NBLK 512
#define FT 1024
#define PS 8            // pool slices: 8 x 64 chunks = 512

typedef _Float16 f16x8 __attribute__((ext_vector_type(8)));
typedef float f32x4 __attribute__((ext_vector_type(4)));

// ---------------------------------------------------------------------------
// K1: hidden = x @ W + b via MFMA (unchanged from round 11 — ~15-20 us,
// near the 16.3 us x-read floor). One wave per 16-node tile, K=256 as
// 8 x mfma_f32_16x16x32_f16; W in 32 VGPRs of B-fragments; zero LDS.
// ---------------------------------------------------------------------------
__global__ void __launch_bounds__(256) hidden_kernel(
    const float* __restrict__ x, const float* __restrict__ W,
    const float* __restrict__ b, __half* __restrict__ hidden, int N) {
    const int lane = threadIdx.x & 63;
    const int wave = (blockIdx.x * blockDim.x + threadIdx.x) >> 6;
    const int m = lane & 15;
    const int kb = lane >> 4;

    const int nTiles = (N + 15) >> 4;
    if (wave >= nTiles) return;

    f16x8 wf[8];
#pragma unroll
    for (int s = 0; s < 8; ++s) {
        const float* wp = W + (size_t)(s * 32 + kb * 8) * NC + m;
        wf[s] = (f16x8){(_Float16)wp[0 * NC], (_Float16)wp[1 * NC],
                        (_Float16)wp[2 * NC], (_Float16)wp[3 * NC],
                        (_Float16)wp[4 * NC], (_Float16)wp[5 * NC],
                        (_Float16)wp[6 * NC], (_Float16)wp[7 * NC]};
    }
    const float bias = b[m];

    const int node0 = wave * 16;
    const int row = min(node0 + m, N - 1);
    const float* xp = x + (size_t)row * DIM + kb * 8;

    float4 ra[8], rb[8];
#pragma unroll
    for (int s = 0; s < 8; ++s) {
        ra[s] = *(const float4*)(xp + s * 32);
        rb[s] = *(const float4*)(xp + s * 32 + 4);
    }

    f32x4 acc = {0.f, 0.f, 0.f, 0.f};
#pragma unroll
    for (int s = 0; s < 8; ++s) {
        f16x8 af = (f16x8){(_Float16)ra[s].x, (_Float16)ra[s].y,
                           (_Float16)ra[s].z, (_Float16)ra[s].w,
                           (_Float16)rb[s].x, (_Float16)rb[s].y,
                           (_Float16)rb[s].z, (_Float16)rb[s].w};
        acc = __builtin_amdgcn_mfma_f32_16x16x32_f16(af, wf[s], acc, 0, 0, 0);
    }

#pragma unroll
    for (int j = 0; j < 4; ++j) {
        int node = node0 + kb * 4 + j;
        if (node < N)
            hidden[(size_t)node * NC + m] = __float2half(acc[j] + bias);
    }
}

// ---------------------------------------------------------------------------
// K2: node -> graph id (searchsorted 'right' over sorted ed_idx)
// ---------------------------------------------------------------------------
__global__ void seg_kernel(const int* __restrict__ ed_idx,
                           int* __restrict__ node_seg, int N, int G) {
    int n = blockIdx.x * blockDim.x + threadIdx.x;
    if (n >= N) return;
    int lo = 0, hi = G;
    while (lo < hi) {
        int mid = (lo + hi) >> 1;
        if (ed_idx[mid] <= n) lo = mid + 1; else hi = mid;
    }
    node_seg[n] = lo;
}

// ---------------------------------------------------------------------------
// K3: per-chunk in-LDS counting sort, then COALESCED concat to global:
// chunkdata[b][0..kept) = g-sorted (col,val); chunkbase[g][b] = run start of
// graph g within chunk b (exclusive scan value, free byproduct).
// No random global scatter (round-4's 73 us flaw) and no in-kernel pool
// (round-5/6's skew tail + conflicted per-lane LDS reads).
// ---------------------------------------------------------------------------
__global__ void __launch_bounds__(FT) sortchunk_kernel(
    const int* __restrict__ rows, const int* __restrict__ cols,
    const float* __restrict__ vals, const int* __restrict__ node_seg,
    uint2* __restrict__ chunkdata, unsigned* __restrict__ chunkbase, int nE) {
    __shared__ unsigned hist[NG];
    __shared__ unsigned cursor[NG];
    __shared__ unsigned wsum[FT / 64];
    __shared__ unsigned keptS;
    __shared__ unsigned short raw_g[CHUNK];
    __shared__ uint2 sorted[CHUNK];

    const int t = threadIdx.x, lane = t & 63, wid = t >> 6;
    const int blk = blockIdx.x;
    const int beg = blk * CHUNK;
    const int cnt = min(nE - beg, CHUNK);

    for (int i = t; i < NG; i += FT) hist[i] = 0u;
    __syncthreads();

    // pass A: g = node_seg[rows[e]]; LDS histogram (2-unrolled ILP)
    for (int i = t; i < cnt; i += 2 * FT) {
        int i2 = i + FT;
        bool ok2 = i2 < cnt;
        int r1 = rows[beg + i];
        int r2 = rows[beg + (ok2 ? i2 : i)];
        int g1 = node_seg[r1];
        int g2 = node_seg[r2];
        raw_g[i] = (unsigned short)g1;
        if (g1 < NG) atomicAdd(&hist[g1], 1u);
        if (ok2) {
            raw_g[i2] = (unsigned short)g2;
            if (g2 < NG) atomicAdd(&hist[g2], 1u);
        }
    }
    __syncthreads();

    // block-wide exclusive scan of hist[0..NG)
    unsigned v = (t < NG) ? hist[t] : 0u;
    unsigned inc = v;
#pragma unroll
    for (int d = 1; d < 64; d <<= 1) {
        unsigned u = __shfl_up(inc, d);
        if (lane >= d) inc += u;
    }
    if (lane == 63) wsum[wid] = inc;
    __syncthreads();
    if (wid == 0) {
        unsigned v2 = (lane < FT / 64) ? wsum[lane] : 0u;
        unsigned inc2 = v2;
#pragma unroll
        for (int d = 1; d < FT / 64; d <<= 1) {
            unsigned u = __shfl_up(inc2, d);
            if (lane >= d) inc2 += u;
        }
        if (lane < FT / 64) wsum[lane] = inc2 - v2;
    }
    __syncthreads();
    unsigned myBeg = wsum[wid] + inc - v;
    if (t < NG) {
        cursor[t] = myBeg;
        chunkbase[(size_t)t * NBLK + blk] = myBeg;
    }
    if (t == NG - 1) {
        chunkbase[(size_t)NG * NBLK + blk] = myBeg + v;
        keptS = myBeg + v;
    }
    __syncthreads();

    // pass B: LDS scatter into g-sorted order
    for (int i = t; i < cnt; i += FT) {
        int g = raw_g[i];
        if (g < NG) {
            unsigned pos = atomicAdd(&cursor[g], 1u);
            sorted[pos] = make_uint2((unsigned)cols[beg + i],
                                     __float_as_uint(vals[beg + i]));
        }
    }
    __syncthreads();

    // coalesced stream-out of the sorted chunk
    const unsigned kept = keptS;
    uint2* dst = chunkdata + (size_t)blk * CHUNK;
    for (unsigned i = t; i < kept; i += FT) dst[i] = sorted[i];
}

// ---------------------------------------------------------------------------
// K4: balanced pool. Block (g, s) covers chunks [s*64, s*64+64); 4 threads
// per chunk-run stride-4 through it (avg 1.6, max ~10 edges/thread).
// Register accumulate -> wave shfl-reduce -> cross-wave LDS -> 16 atomics
// straight into out (reduce_kernel eliminated).
// ---------------------------------------------------------------------------
__global__ void __launch_bounds__(256) pool_kernel(
    const uint2* __restrict__ chunkdata, const __half* __restrict__ hidden,
    const unsigned* __restrict__ chunkbase, float* __restrict__ out) {
    const int g = blockIdx.x >> 3, s = blockIdx.x & (PS - 1);
    const int t = threadIdx.x;
    const int c = s * 64 + (t >> 2);       // chunk 0..511
    const int off0 = t & 3;

    unsigned rbeg = chunkbase[(size_t)g * NBLK + c];
    unsigned rend = chunkbase[(size_t)(g + 1) * NBLK + c];

    float acc[NC];
#pragma unroll
    for (int ch = 0; ch < NC; ++ch) acc[ch] = 0.f;

    const uint2* cd = chunkdata + (size_t)c * CHUNK;
    for (unsigned i = rbeg + off0; i < rend; i += 4) {
        uint2 cv = cd[i];
        float vv = __uint_as_float(cv.y);
        uint4 h0 = *(const uint4*)(hidden + (size_t)cv.x * NC);
        uint4 h1 = *(const uint4*)(hidden + (size_t)cv.x * NC + 8);
        const __half2* q0 = (const __half2*)&h0;
        const __half2* q1 = (const __half2*)&h1;
#pragma unroll
        for (int k = 0; k < 4; ++k) {
            float2 f0 = __half22float2(q0[k]);
            float2 f1 = __half22float2(q1[k]);
            acc[2 * k]         = fmaf(vv, f0.x, acc[2 * k]);
            acc[2 * k + 1]     = fmaf(vv, f0.y, acc[2 * k + 1]);
            acc[8 + 2 * k]     = fmaf(vv, f1.x, acc[8 + 2 * k]);
            acc[8 + 2 * k + 1] = fmaf(vv, f1.y, acc[8 + 2 * k + 1]);
        }
    }

    // wave reduce all 16 channels
#pragma unroll
    for (int ch = 0; ch < NC; ++ch) {
#pragma unroll
        for (int d = 1; d < 64; d <<= 1) acc[ch] += __shfl_xor(acc[ch], d);
    }
    __shared__ float part[4][NC];
    const int lane = t & 63, wv = t >> 6;
    if (lane == 0) {
#pragma unroll
        for (int ch = 0; ch < NC; ++ch) part[wv][ch] = acc[ch];
    }
    __syncthreads();
    if (t < NC) {
        float sum = part[0][t] + part[1][t] + part[2][t] + part[3][t];
        atomicAdd(&out[g * NC + t], sum);
    }
}

extern "C" void kernel_launch(void* const* d_in, const int* in_sizes, int n_in,
                              void* d_out, int out_size, void* d_ws, size_t ws_size,
                              hipStream_t stream) {
    const float* x      = (const float*)d_in[0];
    const int*   ed_idx = (const int*)  d_in[1];
    const int*   rows   = (const int*)  d_in[2];
    const int*   cols   = (const int*)  d_in[3];
    const float* vals   = (const float*)d_in[4];
    const float* W      = (const float*)d_in[5];
    const float* b      = (const float*)d_in[6];
    float* out = (float*)d_out;

    int N  = in_sizes[0] / DIM;   // 100000
    int G  = in_sizes[1];         // 1000
    int nE = in_sizes[2];         // 3200000

    size_t off = 0;
    auto alloc = [&](size_t bytes, size_t align) {
        off = (off + align - 1) / align * align;
        size_t r = off; off += bytes; return r;
    };
    __half*   hidden    = (__half*)  ((char*)d_ws + alloc((size_t)N * NC * 2, 16));
    int*      node_seg  = (int*)     ((char*)d_ws + alloc((size_t)N * 4, 16));
    uint2*    chunkdata = (uint2*)   ((char*)d_ws + alloc((size_t)NBLK * CHUNK * 8, 16));
    unsigned* chunkbase = (unsigned*)((char*)d_ws + alloc((size_t)(NG + 1) * NBLK * 4, 16));
    (void)ws_size;

    (void)hipMemsetAsync(d_out, 0, (size_t)out_size * sizeof(float), stream);

    seg_kernel<<<(N + 255) / 256, 256, 0, stream>>>(ed_idx, node_seg, N, G);
    int nTiles = (N + 15) / 16;
    int hblocks = (nTiles + 3) / 4;
    hidden_kernel<<<hblocks, 256, 0, stream>>>(x, W, b, hidden, N);
    sortchunk_kernel<<<NBLK, FT, 0, stream>>>(rows, cols, vals, node_seg,
                                              chunkdata, chunkbase, nE);
    pool_kernel<<<NG * PS, 256, 0, stream>>>(chunkdata, hidden, chunkbase, out);
}

// Round 13
// 93.891 us; speedup vs baseline: 1.0434x; 1.0434x over previous
//
#include <hip/hip_runtime.h>
#include <hip/hip_fp16.h>

#define DIM 256
#define NC 16
#define NG 1000
#define CHUNK 6250      // 512 * 6250 = 3.2M exactly -> 1 chunk per block
#define NBLK 512
#define FT 1024
#define NJ ((CHUNK + FT - 1) / FT)   // 7 register slots per thread

typedef _Float16 f16x8 __attribute__((ext_vector_type(8)));
typedef float f32x4 __attribute__((ext_vector_type(4)));

// ---------------------------------------------------------------------------
// K1: hidden = x @ W + b via MFMA (unchanged, ~15 us, near x-read floor).
// One wave per 16-node tile, K=256 as 8 x mfma_f32_16x16x32_f16.
// ---------------------------------------------------------------------------
__global__ void __launch_bounds__(256) hidden_kernel(
    const float* __restrict__ x, const float* __restrict__ W,
    const float* __restrict__ b, __half* __restrict__ hidden, int N) {
    const int lane = threadIdx.x & 63;
    const int wave = (blockIdx.x * blockDim.x + threadIdx.x) >> 6;
    const int m = lane & 15;
    const int kb = lane >> 4;

    const int nTiles = (N + 15) >> 4;
    if (wave >= nTiles) return;

    f16x8 wf[8];
#pragma unroll
    for (int s = 0; s < 8; ++s) {
        const float* wp = W + (size_t)(s * 32 + kb * 8) * NC + m;
        wf[s] = (f16x8){(_Float16)wp[0 * NC], (_Float16)wp[1 * NC],
                        (_Float16)wp[2 * NC], (_Float16)wp[3 * NC],
                        (_Float16)wp[4 * NC], (_Float16)wp[5 * NC],
                        (_Float16)wp[6 * NC], (_Float16)wp[7 * NC]};
    }
    const float bias = b[m];

    const int node0 = wave * 16;
    const int row = min(node0 + m, N - 1);
    const float* xp = x + (size_t)row * DIM + kb * 8;

    float4 ra[8], rb[8];
#pragma unroll
    for (int s = 0; s < 8; ++s) {
        ra[s] = *(const float4*)(xp + s * 32);
        rb[s] = *(const float4*)(xp + s * 32 + 4);
    }

    f32x4 acc = {0.f, 0.f, 0.f, 0.f};
#pragma unroll
    for (int s = 0; s < 8; ++s) {
        f16x8 af = (f16x8){(_Float16)ra[s].x, (_Float16)ra[s].y,
                           (_Float16)ra[s].z, (_Float16)ra[s].w,
                           (_Float16)rb[s].x, (_Float16)rb[s].y,
                           (_Float16)rb[s].z, (_Float16)rb[s].w};
        acc = __builtin_amdgcn_mfma_f32_16x16x32_f16(af, wf[s], acc, 0, 0, 0);
    }

#pragma unroll
    for (int j = 0; j < 4; ++j) {
        int node = node0 + kb * 4 + j;
        if (node < N)
            hidden[(size_t)node * NC + m] = __float2half(acc[j] + bias);
    }
}

// ---------------------------------------------------------------------------
// K2: node -> graph id (searchsorted 'right' over sorted ed_idx)
// ---------------------------------------------------------------------------
__global__ void seg_kernel(const int* __restrict__ ed_idx,
                           int* __restrict__ node_seg, int N, int G) {
    int n = blockIdx.x * blockDim.x + threadIdx.x;
    if (n >= N) return;
    int lo = 0, hi = G;
    while (lo < hi) {
        int mid = (lo + hi) >> 1;
        if (ed_idx[mid] <= n) lo = mid + 1; else hi = mid;
    }
    node_seg[n] = lo;
}

// ---------------------------------------------------------------------------
// K3: fused rank-sort + register pooling. ONE atomic pass: pass A's
// atomicAdd returns the within-bin rank; after the scan, pass B writes
// sorted[base[g]+rank] with NO atomics (halves the 35us LDS-atomic term).
// (col,val) and packed (rank<<10|g) stay in 7 statically-indexed registers
// across the scan. Pool: thread t owns graph t's run, prefetch-pipelined
// 32B f16 hidden gathers, coalesced 64KB partial slice per block.
// ---------------------------------------------------------------------------
__global__ void __launch_bounds__(FT) gcn_pool_kernel(
    const int* __restrict__ rows, const int* __restrict__ cols,
    const float* __restrict__ vals, const __half* __restrict__ hidden,
    const int* __restrict__ node_seg, float* __restrict__ partials, int nE) {
    __shared__ unsigned hist[NG];
    __shared__ unsigned basearr[NG];
    __shared__ unsigned wsum[FT / 64];
    __shared__ uint2 sorted[CHUNK];     // 50 KB; total LDS ~58 KB

    const int t = threadIdx.x, lane = t & 63, wid = t >> 6;
    const int beg = blockIdx.x * CHUNK;
    const int cnt = min(nE - beg, CHUNK);

    for (int i = t; i < NG; i += FT) hist[i] = 0u;
    __syncthreads();

    // ---- pass A: load triple, seg lookup, rank-returning atomic ----
    uint2 cv[NJ];
    unsigned pk[NJ];
#pragma unroll
    for (int j = 0; j < NJ; ++j) {
        int i = j * FT + t;
        pk[j] = 0xFFFFFFFFu;
        if (i < cnt) {
            int r = rows[beg + i];
            cv[j] = make_uint2((unsigned)cols[beg + i],
                               __float_as_uint(vals[beg + i]));
            int g = node_seg[r];
            if (g < NG) {
                unsigned rank = atomicAdd(&hist[g], 1u);
                pk[j] = (rank << 10) | (unsigned)g;
            }
        }
    }
    __syncthreads();

    // ---- block-wide exclusive scan of hist[0..NG) ----
    unsigned v = (t < NG) ? hist[t] : 0u;
    unsigned inc = v;
#pragma unroll
    for (int d = 1; d < 64; d <<= 1) {
        unsigned u = __shfl_up(inc, d);
        if (lane >= d) inc += u;
    }
    if (lane == 63) wsum[wid] = inc;
    __syncthreads();
    if (wid == 0) {
        unsigned v2 = (lane < FT / 64) ? wsum[lane] : 0u;
        unsigned inc2 = v2;
#pragma unroll
        for (int d = 1; d < FT / 64; d <<= 1) {
            unsigned u = __shfl_up(inc2, d);
            if (lane >= d) inc2 += u;
        }
        if (lane < FT / 64) wsum[lane] = inc2 - v2;
    }
    __syncthreads();
    unsigned myBeg = wsum[wid] + inc - v;
    if (t < NG) basearr[t] = myBeg;
    __syncthreads();

    // ---- pass B: scatter from registers, NO atomics ----
#pragma unroll
    for (int j = 0; j < NJ; ++j) {
        if (pk[j] != 0xFFFFFFFFu) {
            unsigned g = pk[j] & 1023u;
            sorted[basearr[g] + (pk[j] >> 10)] = cv[j];
        }
    }
    __syncthreads();

    // ---- pool: thread t owns graph t's run [myBeg, myBeg+v) ----
    float acc[NC];
#pragma unroll
    for (int c = 0; c < NC; ++c) acc[c] = 0.f;

    if (t < NG && v) {
        unsigned i = myBeg, end = myBeg + v;
        uint2 cve = sorted[i];
        uint4 h0 = *(const uint4*)(hidden + (size_t)cve.x * NC);
        uint4 h1 = *(const uint4*)(hidden + (size_t)cve.x * NC + 8);
        while (i < end) {
            unsigned nx = i + 1;
            uint2 cvn = cve;
            uint4 h0n = h0, h1n = h1;
            if (nx < end) {                 // prefetch next edge
                cvn = sorted[nx];
                h0n = *(const uint4*)(hidden + (size_t)cvn.x * NC);
                h1n = *(const uint4*)(hidden + (size_t)cvn.x * NC + 8);
            }
            float vv = __uint_as_float(cve.y);
            const __half2* q0 = (const __half2*)&h0;
            const __half2* q1 = (const __half2*)&h1;
#pragma unroll
            for (int k = 0; k < 4; ++k) {
                float2 f0 = __half22float2(q0[k]);
                float2 f1 = __half22float2(q1[k]);
                acc[2 * k]         = fmaf(vv, f0.x, acc[2 * k]);
                acc[2 * k + 1]     = fmaf(vv, f0.y, acc[2 * k + 1]);
                acc[8 + 2 * k]     = fmaf(vv, f1.x, acc[8 + 2 * k]);
                acc[8 + 2 * k + 1] = fmaf(vv, f1.y, acc[8 + 2 * k + 1]);
            }
            cve = cvn; h0 = h0n; h1 = h1n; i = nx;
        }
    }

    if (t < NG) {
        float4* p = (float4*)(partials + ((size_t)blockIdx.x * NG + t) * NC);
        p[0] = make_float4(acc[0], acc[1], acc[2], acc[3]);
        p[1] = make_float4(acc[4], acc[5], acc[6], acc[7]);
        p[2] = make_float4(acc[8], acc[9], acc[10], acc[11]);
        p[3] = make_float4(acc[12], acc[13], acc[14], acc[15]);
    }
}

// ---------------------------------------------------------------------------
// K4: fold partials[NBLK][NG*NC] into out; blockIdx.y picks 64 slices.
// ---------------------------------------------------------------------------
__global__ void reduce_kernel(const float* __restrict__ partials,
                              float* __restrict__ out) {
    int i = blockIdx.x * blockDim.x + threadIdx.x;
    if (i >= NG * NC) return;
    const int per = NBLK / 8;  // 64
    const float* p = partials + (size_t)(blockIdx.y * per) * (NG * NC) + i;
    float s0 = 0.f, s1 = 0.f, s2 = 0.f, s3 = 0.f;
#pragma unroll 4
    for (int k = 0; k < per; k += 4) {
        s0 += p[(size_t)(k + 0) * (NG * NC)];
        s1 += p[(size_t)(k + 1) * (NG * NC)];
        s2 += p[(size_t)(k + 2) * (NG * NC)];
        s3 += p[(size_t)(k + 3) * (NG * NC)];
    }
    atomicAdd(&out[i], (s0 + s1) + (s2 + s3));
}

extern "C" void kernel_launch(void* const* d_in, const int* in_sizes, int n_in,
                              void* d_out, int out_size, void* d_ws, size_t ws_size,
                              hipStream_t stream) {
    const float* x      = (const float*)d_in[0];
    const int*   ed_idx = (const int*)  d_in[1];
    const int*   rows   = (const int*)  d_in[2];
    const int*   cols   = (const int*)  d_in[3];
    const float* vals   = (const float*)d_in[4];
    const float* W      = (const float*)d_in[5];
    const float* b      = (const float*)d_in[6];
    float* out = (float*)d_out;

    int N  = in_sizes[0] / DIM;   // 100000
    int G  = in_sizes[1];         // 1000
    int nE = in_sizes[2];         // 3200000

    size_t off = 0;
    auto alloc = [&](size_t bytes, size_t align) {
        off = (off + align - 1) / align * align;
        size_t r = off; off += bytes; return r;
    };
    __half* hidden   = (__half*)((char*)d_ws + alloc((size_t)N * NC * 2, 16));
    int*    node_seg = (int*)   ((char*)d_ws + alloc((size_t)N * 4, 16));
    float*  partials = (float*) ((char*)d_ws + alloc((size_t)NBLK * NG * NC * 4, 16));
    (void)ws_size;

    (void)hipMemsetAsync(d_out, 0, (size_t)out_size * sizeof(float), stream);

    seg_kernel<<<(N + 255) / 256, 256, 0, stream>>>(ed_idx, node_seg, N, G);
    int nTiles = (N + 15) / 16;
    int hblocks = (nTiles + 3) / 4;
    hidden_kernel<<<hblocks, 256, 0, stream>>>(x, W, b, hidden, N);
    gcn_pool_kernel<<<NBLK, FT, 0, stream>>>(rows, cols, vals, hidden,
                                             node_seg, partials, nE);
    dim3 rg((NG * NC + 255) / 256, 8);
    reduce_kernel<<<rg, 256, 0, stream>>>(partials, out);
}